// Round 7
// baseline (224.537 us; speedup 1.0000x reference)
//
#include <hip/hip_runtime.h>

#define TPB 256

// Fused CIoU, 1 thread/element (r5 skeleton — the only codegen shape that
// has allocated cleanly; r3/r4: arrays->scratch, r6: shuffles-in-loop->scratch).
// Intersection area via Green's theorem on clipped edges:
//   2*area(A∩B) = sum over directed edges of each polygon of
//                 cross(P(t0),P(t1)), [t0,t1] clipped to the other's planes.
// Improvements over r5: hoisted edge vectors + per-plane constants cQ
// (aa = Ex*Py - Ey*Px - cQ : 2 fma), ±inf interval trick with tree min/max
// (r6-validated), tree-combine Jarvis scan (r6-validated logic, no shuffles).
__global__ __launch_bounds__(TPB, 3) void ciou_fused(
    const float* __restrict__ A,
    const float* __restrict__ Bq,
    float* __restrict__ out,
    double* __restrict__ acc,
    unsigned int* __restrict__ cnt,
    int nbatch, int nblocks)
{
    const int t = threadIdx.x;
    const int i0 = blockIdx.x * TPB + t;
    const bool live = (i0 < nbatch);
    const int i = live ? i0 : (nbatch - 1);
    float val = 0.f;

    float ax0,ax1,ax2,ax3,ax4,ax5,ax6,ax7;
    float ay0,ay1,ay2,ay3,ay4,ay5,ay6,ay7;
    float bx0,bx1,bx2,bx3,bx4,bx5,bx6,bx7;
    float by0,by1,by2,by3,by4,by5,by6,by7;
    {
        const float4* pa = (const float4*)(A + (size_t)i * 16);
        const float4* pb = (const float4*)(Bq + (size_t)i * 16);
        float4 q;
        q = pa[0]; ax0=q.x; ay0=q.y; ax1=q.z; ay1=q.w;
        q = pa[1]; ax2=q.x; ay2=q.y; ax3=q.z; ay3=q.w;
        q = pa[2]; ax4=q.x; ay4=q.y; ax5=q.z; ay5=q.w;
        q = pa[3]; ax6=q.x; ay6=q.y; ax7=q.z; ay7=q.w;
        q = pb[0]; bx0=q.x; by0=q.y; bx1=q.z; by1=q.w;
        q = pb[1]; bx2=q.x; by2=q.y; bx3=q.z; by3=q.w;
        q = pb[2]; bx4=q.x; by4=q.y; bx5=q.z; by5=q.w;
        q = pb[3]; bx6=q.x; by6=q.y; bx7=q.z; by7=q.w;
    }

    // Hoisted edge vectors.
    float eax0=ax1-ax0, eay0=ay1-ay0, eax1=ax2-ax1, eay1=ay2-ay1;
    float eax2=ax3-ax2, eay2=ay3-ay2, eax3=ax4-ax3, eay3=ay4-ay3;
    float eax4=ax5-ax4, eay4=ay5-ay4, eax5=ax6-ax5, eay5=ay6-ay5;
    float eax6=ax7-ax6, eay6=ay7-ay6, eax7=ax0-ax7, eay7=ay0-ay7;
    float ebx0=bx1-bx0, eby0=by1-by0, ebx1=bx2-bx1, eby1=by2-by1;
    float ebx2=bx3-bx2, eby2=by3-by2, ebx3=bx4-bx3, eby3=by4-by3;
    float ebx4=bx5-bx4, eby4=by5-by4, ebx5=bx6-bx5, eby5=by6-by5;
    float ebx6=bx7-bx6, eby6=by7-by6, ebx7=bx0-bx7, eby7=by0-by7;

    // Per-plane constants cQ = cross(E, V) = Ex*Vy - Ey*Vx.
    float cA0=eax0*ay0-eay0*ax0, cA1=eax1*ay1-eay1*ax1;
    float cA2=eax2*ay2-eay2*ax2, cA3=eax3*ay3-eay3*ax3;
    float cA4=eax4*ay4-eay4*ax4, cA5=eax5*ay5-eay5*ax5;
    float cA6=eax6*ay6-eay6*ax6, cA7=eax7*ay7-eay7*ax7;
    float cB0=ebx0*by0-eby0*bx0, cB1=ebx1*by1-eby1*bx1;
    float cB2=ebx2*by2-eby2*bx2, cB3=ebx3*by3-eby3*bx3;
    float cB4=ebx4*by4-eby4*bx4, cB5=ebx5*by5-eby5*bx5;
    float cB6=ebx6*by6-eby6*bx6, cB7=ebx7*by7-eby7*bx7;

    // Shoelace for free: area = -1/2 * sum(cQ)  (input CCW; sort_poly = rotation)
    float area_a = -0.5f * (cA0+cA1+cA2+cA3+cA4+cA5+cA6+cA7);
    float area_b = -0.5f * (cB0+cB1+cB2+cB3+cB4+cB5+cB6+cB7);

    // ---- Intersection: Green's theorem over clipped edges ----
    const float INFP = __builtin_inff();
    float inter2 = 0.f;

    // inside Q at param t along P-edge: aa + t*bb >= 0, aa = Ex*Py-Ey*Px-cQ
#define HP(J,EX,EY,CQ) \
    float e0_##J, e1_##J; { \
        float aa = (EX)*Py - (EY)*Px - (CQ); \
        float bb = (EX)*Dy - (EY)*Dx; \
        float tc = __fdividef(-aa, bb); \
        e0_##J = (bb > 0.f) ? tc : -INFP; \
        e1_##J = (bb < 0.f) ? tc :  INFP; }

#define CLIPB HP(0,ebx0,eby0,cB0) HP(1,ebx1,eby1,cB1) HP(2,ebx2,eby2,cB2) \
              HP(3,ebx3,eby3,cB3) HP(4,ebx4,eby4,cB4) HP(5,ebx5,eby5,cB5) \
              HP(6,ebx6,eby6,cB6) HP(7,ebx7,eby7,cB7)
#define CLIPA HP(0,eax0,eay0,cA0) HP(1,eax1,eay1,cA1) HP(2,eax2,eay2,cA2) \
              HP(3,eax3,eay3,cA3) HP(4,eax4,eay4,cA4) HP(5,eax5,eay5,cA5) \
              HP(6,eax6,eay6,cA6) HP(7,eax7,eay7,cA7)

#define EDGE(PX,PY,DX,DY,CLIPS) { \
        const float Px = (PX), Py = (PY); \
        const float Dx = (DX), Dy = (DY); \
        CLIPS \
        float t0 = fmaxf(0.f, fmaxf(fmaxf(fmaxf(e0_0,e0_1), fmaxf(e0_2,e0_3)), \
                                    fmaxf(fmaxf(e0_4,e0_5), fmaxf(e0_6,e0_7)))); \
        float t1 = fminf(1.f, fminf(fminf(fminf(e1_0,e1_1), fminf(e1_2,e1_3)), \
                                    fminf(fminf(e1_4,e1_5), fminf(e1_6,e1_7)))); \
        float P0x = fmaf(t0,Dx,Px), P0y = fmaf(t0,Dy,Py); \
        float P1x = fmaf(t1,Dx,Px), P1y = fmaf(t1,Dy,Py); \
        inter2 += (t1 > t0) ? (P0x*P1y - P0y*P1x) : 0.f; }

    EDGE(ax0,ay0,eax0,eay0,CLIPB) EDGE(ax1,ay1,eax1,eay1,CLIPB)
    EDGE(ax2,ay2,eax2,eay2,CLIPB) EDGE(ax3,ay3,eax3,eay3,CLIPB)
    EDGE(ax4,ay4,eax4,eay4,CLIPB) EDGE(ax5,ay5,eax5,eay5,CLIPB)
    EDGE(ax6,ay6,eax6,eay6,CLIPB) EDGE(ax7,ay7,eax7,eay7,CLIPB)
    EDGE(bx0,by0,ebx0,eby0,CLIPA) EDGE(bx1,by1,ebx1,eby1,CLIPA)
    EDGE(bx2,by2,ebx2,eby2,CLIPA) EDGE(bx3,by3,ebx3,eby3,CLIPA)
    EDGE(bx4,by4,ebx4,eby4,CLIPA) EDGE(bx5,by5,ebx5,eby5,CLIPA)
    EDGE(bx6,by6,ebx6,eby6,CLIPA) EDGE(bx7,by7,ebx7,eby7,CLIPA)

    float inter = fmaxf(0.5f * inter2, 0.f);
    float uni = area_a + area_b - inter;
    float iou = __fdividef(inter, uni);

    // ---- Hull start: min by (y, x), tree ----
#define MINP(OX,OY,X1,Y1,X2,Y2) \
    float OX, OY; { bool s2 = ((Y2) < (Y1)) || (((Y2) == (Y1)) && ((X2) < (X1))); \
        OX = s2 ? (X2) : (X1); OY = s2 ? (Y2) : (Y1); }
    MINP(m0x,m0y, ax0,ay0, ax1,ay1)  MINP(m1x,m1y, ax2,ay2, ax3,ay3)
    MINP(m2x,m2y, ax4,ay4, ax5,ay5)  MINP(m3x,m3y, ax6,ay6, ax7,ay7)
    MINP(m4x,m4y, bx0,by0, bx1,by1)  MINP(m5x,m5y, bx2,by2, bx3,by3)
    MINP(m6x,m6y, bx4,by4, bx5,by5)  MINP(m7x,m7y, bx6,by6, bx7,by7)
    MINP(n0x,n0y, m0x,m0y, m1x,m1y)  MINP(n1x,n1y, m2x,m2y, m3x,m3y)
    MINP(n2x,n2y, m4x,m4y, m5x,m5y)  MINP(n3x,n3y, m6x,m6y, m7x,m7y)
    MINP(o0x,o0y, n0x,n0y, n1x,n1y)  MINP(o1x,o1y, n2x,n2y, n3x,n3y)
    MINP(stx,sty, o0x,o0y, o1x,o1y)

    // ---- Jarvis march over 16 points, tree-combined scan (no shuffles) ----
    float cxv = stx, cyv = sty, accH = 0.f;
    bool done = false;
    for (int it = 0; it < 16; ++it) {
#define LEAF(K,PX,PY) \
        float vxL##K = (PX) - cxv, vyL##K = (PY) - cyv; \
        bool vvL##K = (vxL##K*vxL##K + vyL##K*vyL##K) > 1e-16f;
        LEAF(0,ax0,ay0) LEAF(1,ax1,ay1) LEAF(2,ax2,ay2) LEAF(3,ax3,ay3)
        LEAF(4,ax4,ay4) LEAF(5,ax5,ay5) LEAF(6,ax6,ay6) LEAF(7,ax7,ay7)
        LEAF(8,bx0,by0) LEAF(9,bx1,by1) LEAF(10,bx2,by2) LEAF(11,bx3,by3)
        LEAF(12,bx4,by4) LEAF(13,bx5,by5) LEAF(14,bx6,by6) LEAF(15,bx7,by7)
        // take R iff R valid and (L invalid or R strictly clockwise of L)
#define COMB1(D,K1,PX1,PY1,K2,PX2,PY2) \
        float vx##D, vy##D, wx##D, wy##D; bool vv##D; { \
            float cr = vxL##K1 * vyL##K2 - vyL##K1 * vxL##K2; \
            bool tk = vvL##K2 && (!vvL##K1 || cr < 0.f); \
            vx##D = tk ? vxL##K2 : vxL##K1;  vy##D = tk ? vyL##K2 : vyL##K1; \
            wx##D = tk ? (PX2) : (PX1);      wy##D = tk ? (PY2) : (PY1); \
            vv##D = vvL##K1 || vvL##K2; }
#define COMB(D,L,R) \
        float vx##D, vy##D, wx##D, wy##D; bool vv##D; { \
            float cr = vx##L * vy##R - vy##L * vx##R; \
            bool tk = vv##R && (!vv##L || cr < 0.f); \
            vx##D = tk ? vx##R : vx##L;  vy##D = tk ? vy##R : vy##L; \
            wx##D = tk ? wx##R : wx##L;  wy##D = tk ? wy##R : wy##L; \
            vv##D = vv##L || vv##R; }
        COMB1(c0, 0,ax0,ay0, 1,ax1,ay1)   COMB1(c1, 2,ax2,ay2, 3,ax3,ay3)
        COMB1(c2, 4,ax4,ay4, 5,ax5,ay5)   COMB1(c3, 6,ax6,ay6, 7,ax7,ay7)
        COMB1(c4, 8,bx0,by0, 9,bx1,by1)   COMB1(c5, 10,bx2,by2, 11,bx3,by3)
        COMB1(c6, 12,bx4,by4, 13,bx5,by5) COMB1(c7, 14,bx6,by6, 15,bx7,by7)
        COMB(d0, c0, c1)  COMB(d1, c2, c3)
        COMB(d2, c4, c5)  COMB(d3, c6, c7)
        COMB(f0, d0, d1)  COMB(f1, d2, d3)
        COMB(rr, f0, f1)
        float nx = wxrr, ny = wyrr;
        accH += done ? 0.f : (cxv * ny - cyv * nx);
        done = done || (nx == stx && ny == sty);
        cxv = nx; cyv = ny;
        if (__all(done)) break;
    }
    float ch = 0.5f * accH;

    val = iou - __fdividef(ch - uni, ch);
    float v = live ? val : 0.f;

    // ---- reduction: wave shuffle -> LDS(16B) -> global double atomic ----
    #pragma unroll
    for (int off = 32; off > 0; off >>= 1) v += __shfl_down(v, off);
    __shared__ float wsum[4];
    int lane = t & 63, wid = t >> 6;
    if (lane == 0) wsum[wid] = v;
    __syncthreads();
    if (t == 0) {
        double bsum = (double)wsum[0] + (double)wsum[1]
                    + (double)wsum[2] + (double)wsum[3];
        atomicAdd(acc, bsum);
        __threadfence();
        unsigned int old = atomicAdd(cnt, 1u);
        if (old == (unsigned int)(nblocks - 1)) {
            double total = atomicAdd(acc, 0.0);   // read after all adds visible
            out[0] = (float)(total / (double)nbatch);
        }
    }
}

extern "C" void kernel_launch(void* const* d_in, const int* in_sizes, int n_in,
                              void* d_out, int out_size, void* d_ws, size_t ws_size,
                              hipStream_t stream) {
    const float* a = (const float*)d_in[0];
    const float* b = (const float*)d_in[1];
    float* out = (float*)d_out;
    int nbatch = in_sizes[0] / 16;
    int nblocks = (nbatch + TPB - 1) / TPB;
    double* acc = (double*)d_ws;                          // [0,8): double sum
    unsigned int* cnt = (unsigned int*)((char*)d_ws + 8); // [8,12): counter
    hipMemsetAsync(d_ws, 0, 16, stream);
    ciou_fused<<<nblocks, TPB, 0, stream>>>(a, b, out, acc, cnt, nbatch, nblocks);
}

// Round 8
// 161.367 us; speedup vs baseline: 1.3915x; 1.3915x over previous
//
#include <hip/hip_runtime.h>

#define TPB 256

// Fused CIoU, 2 threads per element, r5 codegen style throughout.
// Even lane: P=A,Q=B; odd lane: P=B,Q=A — same instruction stream, results
// merged with __shfl_xor(.,1) (pair is always within one wave).
//
// Codegen rule learned r3/r4/r6/r7: the gfx950 backend spills pressure
// PEAKS to scratch (catastrophic) instead of using launch-bounds headroom.
// Therefore: serial half-plane chain (2 live temps), serial march scan
// (~8 live temps), no hoisted cross-block values, no select trees.
__global__ __launch_bounds__(TPB, 6) void ciou_fused(
    const float* __restrict__ A,
    const float* __restrict__ Bq,
    float* __restrict__ out,
    double* __restrict__ acc,
    unsigned int* __restrict__ cnt,
    int nbatch, int nblocks)
{
    const int t = threadIdx.x;
    const int gtid = blockIdx.x * TPB + t;      // max 524288, fits int
    int elem = gtid >> 1;
    const int par = gtid & 1;
    const bool live = (elem < nbatch);
    if (!live) elem = nbatch - 1;

    const float* baseP = par ? Bq : A;
    const float* baseQ = par ? A : Bq;

    float px0,px1,px2,px3,px4,px5,px6,px7;
    float py0,py1,py2,py3,py4,py5,py6,py7;
    float qx0,qx1,qx2,qx3,qx4,qx5,qx6,qx7;
    float qy0,qy1,qy2,qy3,qy4,qy5,qy6,qy7;
    {
        const float4* pp = (const float4*)(baseP + (size_t)elem * 16);
        const float4* pq = (const float4*)(baseQ + (size_t)elem * 16);
        float4 q;
        q = pp[0]; px0=q.x; py0=q.y; px1=q.z; py1=q.w;
        q = pp[1]; px2=q.x; py2=q.y; px3=q.z; py3=q.w;
        q = pp[2]; px4=q.x; py4=q.y; px5=q.z; py5=q.w;
        q = pp[3]; px6=q.x; py6=q.y; px7=q.z; py7=q.w;
        q = pq[0]; qx0=q.x; qy0=q.y; qx1=q.z; qy1=q.w;
        q = pq[1]; qx2=q.x; qy2=q.y; qx3=q.z; qy3=q.w;
        q = pq[2]; qx4=q.x; qy4=q.y; qx5=q.z; qy5=q.w;
        q = pq[3]; qx6=q.x; qy6=q.y; qx7=q.z; qy7=q.w;
    }

    // Shoelace of own polygon (input CCW; sort_poly is a pure rotation).
    float areaP = 0.5f * ((px0*py1-py0*px1) + (px1*py2-py1*px2)
                        + (px2*py3-py2*px3) + (px3*py4-py3*px4)
                        + (px4*py5-py4*px5) + (px5*py6-py5*px6)
                        + (px6*py7-py6*px7) + (px7*py0-py7*px0));
    float sumArea = areaP + __shfl_xor(areaP, 1);  // area_a + area_b

    // ---- Clip own 8 edges vs Q's 8 half-planes (Green's theorem) ----
    // Serial t0/t1 updates: 2 live temps, exactly r5's proven-clean form.
    float inter2s = 0.f;

#define HP(QX0,QY0,QX1,QY1) { \
        float ex = (QX1)-(QX0), ey = (QY1)-(QY0); \
        float aa = ex*(Py-(QY0)) - ey*(Px-(QX0)); \
        float bb = ex*Dy - ey*Dx; \
        float tc = __fdividef(-aa, bb); \
        bool bp = bb > 0.f, bn = bb < 0.f; \
        t0 = (bp && tc > t0) ? tc : t0; \
        t1 = (bn && tc < t1) ? tc : t1; }

#define EDGE(PX,PY,NX,NY) { \
        const float Px = (PX), Py = (PY); \
        const float Dx = (NX) - Px, Dy = (NY) - Py; \
        float t0 = 0.f, t1 = 1.f; \
        HP(qx0,qy0,qx1,qy1) HP(qx1,qy1,qx2,qy2) \
        HP(qx2,qy2,qx3,qy3) HP(qx3,qy3,qx4,qy4) \
        HP(qx4,qy4,qx5,qy5) HP(qx5,qy5,qx6,qy6) \
        HP(qx6,qy6,qx7,qy7) HP(qx7,qy7,qx0,qy0) \
        float P0x = fmaf(t0,Dx,Px), P0y = fmaf(t0,Dy,Py); \
        float P1x = fmaf(t1,Dx,Px), P1y = fmaf(t1,Dy,Py); \
        inter2s += (t1 > t0) ? (P0x*P1y - P0y*P1x) : 0.f; }

    EDGE(px0,py0,px1,py1) EDGE(px1,py1,px2,py2)
    EDGE(px2,py2,px3,py3) EDGE(px3,py3,px4,py4)
    EDGE(px4,py4,px5,py5) EDGE(px5,py5,px6,py6)
    EDGE(px6,py6,px7,py7) EDGE(px7,py7,px0,py0)

    float inter2 = inter2s + __shfl_xor(inter2s, 1);
    float inter = fmaxf(0.5f * inter2, 0.f);
    float uni = sumArea - inter;
    float iou = __fdividef(inter, uni);

    // ---- Hull start: serial min by (y,x) over own 8, one pair-merge ----
    float ssx = px0, ssy = py0;
#define UPD(PX,PY) { \
        bool bs = ((PY) < ssy) || (((PY) == ssy) && ((PX) < ssx)); \
        ssx = bs ? (PX) : ssx; ssy = bs ? (PY) : ssy; }
    UPD(px1,py1) UPD(px2,py2) UPD(px3,py3) UPD(px4,py4)
    UPD(px5,py5) UPD(px6,py6) UPD(px7,py7)
    float stx, sty;
    {
        float osx = __shfl_xor(ssx, 1), osy = __shfl_xor(ssy, 1);
        bool bs = (osy < ssy) || ((osy == ssy) && (osx < ssx));
        stx = bs ? osx : ssx;
        sty = bs ? osy : ssy;
    }

    // ---- Jarvis march: serial scan of OWN 8 points + pair-merge ----
    // (Q coords are dead here -> small live set inside the loop.)
    float cxv = stx, cyv = sty, accH = 0.f;
    bool done = false;
    for (int it = 0; it < 16; ++it) {
        float nx = cxv, ny = cyv, cdx = 0.f, cdy = 0.f;
        bool cv = false;
#define SCAN(PX,PY) { \
            float vx = (PX) - cxv, vy = (PY) - cyv; \
            bool valid = (vx*vx + vy*vy) > 1e-16f; \
            float cr = cdx*vy - cdy*vx; \
            bool take = valid && (!cv || cr < 0.f); \
            nx = take ? (PX) : nx;  ny = take ? (PY) : ny; \
            cdx = take ? vx : cdx;  cdy = take ? vy : cdy; \
            cv = cv || valid; }
        SCAN(px0,py0) SCAN(px1,py1) SCAN(px2,py2) SCAN(px3,py3)
        SCAN(px4,py4) SCAN(px5,py5) SCAN(px6,py6) SCAN(px7,py7)
        // pair-merge: own candidate always valid (>=7 distinct own points).
        // cross antisymmetry -> both lanes converge to the same next vertex
        // (validated end-to-end in r6, absmax 0.0).
        float ovx = __shfl_xor(cdx, 1), ovy = __shfl_xor(cdy, 1);
        float onx = __shfl_xor(nx, 1),  ony = __shfl_xor(ny, 1);
        float crm = cdx * ovy - cdy * ovx;
        bool tko = (crm < 0.f);
        nx = tko ? onx : nx;
        ny = tko ? ony : ny;
        accH += done ? 0.f : (cxv * ny - cyv * nx);
        done = done || (nx == stx && ny == sty);
        cxv = nx; cyv = ny;
        if (__all(done)) break;
    }
    float ch = 0.5f * accH;

    float val = iou - __fdividef(ch - uni, ch);
    float v = live ? 0.5f * val : 0.f;   // identical on both lanes; pair sums to val

    // ---- reduction: wave shuffle -> LDS(16B) -> global double atomic ----
    #pragma unroll
    for (int off = 32; off > 0; off >>= 1) v += __shfl_down(v, off);
    __shared__ float wsum[4];
    int lane = t & 63, wid = t >> 6;
    if (lane == 0) wsum[wid] = v;
    __syncthreads();
    if (t == 0) {
        double bsum = (double)wsum[0] + (double)wsum[1]
                    + (double)wsum[2] + (double)wsum[3];
        atomicAdd(acc, bsum);
        __threadfence();
        unsigned int old = atomicAdd(cnt, 1u);
        if (old == (unsigned int)(nblocks - 1)) {
            double total = atomicAdd(acc, 0.0);   // read after all adds visible
            out[0] = (float)(total / (double)nbatch);
        }
    }
}

extern "C" void kernel_launch(void* const* d_in, const int* in_sizes, int n_in,
                              void* d_out, int out_size, void* d_ws, size_t ws_size,
                              hipStream_t stream) {
    const float* a = (const float*)d_in[0];
    const float* b = (const float*)d_in[1];
    float* out = (float*)d_out;
    int nbatch = in_sizes[0] / 16;
    int nblocks = (2 * nbatch + TPB - 1) / TPB;
    double* acc = (double*)d_ws;                          // [0,8): double sum
    unsigned int* cnt = (unsigned int*)((char*)d_ws + 8); // [8,12): counter
    hipMemsetAsync(d_ws, 0, 16, stream);
    ciou_fused<<<nblocks, TPB, 0, stream>>>(a, b, out, acc, cnt, nbatch, nblocks);
}